// Round 9
// baseline (94.820 us; speedup 1.0000x reference)
//
#include <hip/hip_runtime.h>
#include <cstddef>

// Block-cooperative MFMA MixModel, 32 rows/tile, swapped-operand GEMMs:
//   GEMM1 (swapped): D = mfma(W1frag, u_frag) = h^T tile -> lane holds
//     h[row=ln][4 consecutive hidden units] -> tanh+pack -> 1 ds_write_b64.
//   GEMM2 (swapped): D = mfma(W2frag, h_frag) = C2^T tile -> lane holds
//     C2[row=ln][4 consecutive features] -> quad-interleaved c2s write is one
//     ds_write_b128 for the odd-section waves (W2b at internal offset 56).
// Fragment data is IDENTICAL to the R8-verified kernel (A/B lane maps match);
// only mfma argument order + bias vectors + write addressing change.
// u staging, h_sh layout/reads, epilogue: byte-identical to R8 (HW-verified).

typedef __attribute__((ext_vector_type(8))) __bf16 bf16x8;
typedef __attribute__((ext_vector_type(8))) short short8;
typedef __attribute__((ext_vector_type(4))) float f32x4;

__device__ __forceinline__ unsigned short f2bf(float f) {
    // manual RNE float->bf16 (R4/R6/R8-verified)
    unsigned int u = __float_as_uint(f);
    unsigned int r = (u + 0x7FFFu + ((u >> 16) & 1u)) >> 16;
    return (unsigned short)r;
}

// --- mfma wrapper: tolerate either V8bf16 or V8i16 builtin signature ---
template <typename A>
__device__ __forceinline__ auto mfma_try(A a, A b, f32x4 c, int)
    -> decltype(__builtin_amdgcn_mfma_f32_16x16x32_bf16(a, b, c, 0, 0, 0)) {
    return __builtin_amdgcn_mfma_f32_16x16x32_bf16(a, b, c, 0, 0, 0);
}
template <typename A>
__device__ __forceinline__ f32x4 mfma_try(A a, A b, f32x4 c, long) {
    return __builtin_amdgcn_mfma_f32_16x16x32_bf16(
        __builtin_bit_cast(short8, a), __builtin_bit_cast(short8, b), c, 0, 0, 0);
}
__device__ __forceinline__ f32x4 mfma_bf16(short8 a, short8 b, f32x4 c) {
    return mfma_try(__builtin_bit_cast(bf16x8, a), __builtin_bit_cast(bf16x8, b), c, 0);
}

__device__ __forceinline__ float tanh_fast(float x) {
    const float e2 = __expf(2.0f * x);
    return 1.0f - __fdividef(2.0f, e2 + 1.0f);
}

__global__ __launch_bounds__(256, 4) void mixmodel_mfma9(
    const float* __restrict__ u,      // N*36
    const float* __restrict__ reg1,   // 6
    const float* __restrict__ reg2,   // 4
    const float* __restrict__ W1,     // 18*128
    const float* __restrict__ b1,     // 128
    const float* __restrict__ W2a,    // 128*54
    const float* __restrict__ b2a,    // 54
    const float* __restrict__ W2b,    // 128*72
    const float* __restrict__ b2b,    // 72
    float* __restrict__ out,          // N*36
    int N, int ntiles)
{
    __shared__ __align__(16) float          u_ext[32 * 40];   // 5120 B
    __shared__ __align__(16) unsigned short h_sh[32 * 136];   // 8704 B (verified layout)
    __shared__ __align__(16) unsigned short u_bf[32 * 32];    // 2048 B
    __shared__ __align__(16) float          c2s[32 * 144];    // 18432 B, [row][8i+slot]
    // total = 34304 B -> 4 blocks/CU

    const int tid = threadIdx.x;
    const int wid = tid >> 6;
    const int l   = tid & 63;
    const int ln  = l & 15;
    const int lg  = l >> 4;
    const int nb  = wid * 32;

    reinterpret_cast<unsigned int*>(u_bf)[tid]       = 0u;
    reinterpret_cast<unsigned int*>(u_bf)[tid + 256] = 0u;
    __syncthreads();

    // ---- internal feature map: [0,54) = W2a col n; 54,55 = zero; [56,128) = W2b col n-56 ----
    // ---- resident weight fragments (lane dim = ln): 40 VGPRs, same data as R8 ----
    short8 b1f[2];
    short8 b2f[2][4];
#pragma unroll
    for (int t = 0; t < 2; ++t) {
        const int n = nb + t * 16 + ln;   // fragment row index (A-operand row = ln)
        short8 v;
#pragma unroll
        for (int j = 0; j < 8; ++j) {
            const int k = lg * 8 + j;
            const float w = (k < 18) ? W1[k * 128 + n] : 0.0f;
            v[j] = (short)f2bf(w);
        }
        b1f[t] = v;
#pragma unroll
        for (int kk = 0; kk < 4; ++kk) {
            short8 w2;
#pragma unroll
            for (int j = 0; j < 8; ++j) {
                const int k = kk * 32 + lg * 8 + j;
                float w;
                if (n < 54)       w = W2a[k * 54 + n];
                else if (n < 56)  w = 0.0f;                 // dummy features
                else              w = W2b[k * 72 + (n - 56)];
                w2[j] = (short)f2bf(w);
            }
            b2f[t][kk] = w2;
        }
    }

    // ---- per-reg bias vectors + C2 write slots (lane dim = lg*4+r) ----
    f32x4 bias1v[2], bias2v[2];
    int  c2slot[2][4];   // scalar slots (or slot0 in [0] for vector path); -1 = skip
    bool c2vec[2];
#pragma unroll
    for (int t = 0; t < 2; ++t) {
        const int n0 = nb + t * 16 + lg * 4;
        bias1v[t] = *reinterpret_cast<const f32x4*>(&b1[n0]);
        f32x4 bv;
#pragma unroll
        for (int r = 0; r < 4; ++r) {
            const int n = n0 + r;
            bv[r] = (n < 54) ? b2a[n] : (n < 56 ? 0.0f : b2b[n - 56]);
            c2slot[t][r] = (n < 54) ? (8 * (n / 3) + n % 3) : -1;
        }
        bias2v[t] = bv;
        c2vec[t] = (n0 >= 56);
        if (c2vec[t]) c2slot[t][0] = 8 * ((n0 - 56) >> 2) + 4;
    }

    // ---- regression coefficients (wave-uniform -> SGPR) ----
    const float r10 = reg1[0], r11 = reg1[1], r12 = reg1[2];
    const float r13 = reg1[3], r14 = reg1[4], r15 = reg1[5];
    const float r20 = reg2[0], r21 = reg2[1], r22 = reg2[2], r23 = reg2[3];

    const float4* ug = reinterpret_cast<const float4*>(u);
    const long fmax4 = (long)N * 9 - 1;
    const int gs = gridDim.x;

    // ---- staging maps (R8-verified) ----
    const int row0 = tid / 9,          c0 = tid - row0 * 9;
    const int row1 = (256 + tid) / 9,  c1 = (256 + tid) - row1 * 9;
    const int hrow = (tid - 192) >> 1, hside = tid & 1;

    float4 pf0, pf1; float2 pfh;
    {
        const int r0 = blockIdx.x * 32;
        long g0 = (long)r0 * 9 + tid; if (g0 > fmax4) g0 = fmax4;
        pf0 = ug[g0];
        if (tid < 32) {
            long g1 = (long)r0 * 9 + 256 + tid; if (g1 > fmax4) g1 = fmax4;
            pf1 = ug[g1];
        }
        if (tid >= 192) {
            int rr = r0 + hrow; if (rr > N - 1) rr = N - 1;
            pfh = *reinterpret_cast<const float2*>(u + (size_t)rr * 36 + (hside ? 0 : 34));
        }
    }

    for (int tile = blockIdx.x; tile < ntiles; tile += gs) {
        // ---- stage u_ext / u_bf; prefetch next ----
        {
            float* dst = &u_ext[row0 * 40 + 2 + c0 * 4];
            reinterpret_cast<float2*>(dst)[0] = make_float2(pf0.x, pf0.y);
            reinterpret_cast<float2*>(dst)[1] = make_float2(pf0.z, pf0.w);
            reinterpret_cast<unsigned int*>(u_bf)[row0 * 16 + c0] =
                (unsigned int)f2bf(pf0.x) | ((unsigned int)f2bf(pf0.z) << 16);
            if (tid < 32) {
                float* dst1 = &u_ext[row1 * 40 + 2 + c1 * 4];
                reinterpret_cast<float2*>(dst1)[0] = make_float2(pf1.x, pf1.y);
                reinterpret_cast<float2*>(dst1)[1] = make_float2(pf1.z, pf1.w);
                reinterpret_cast<unsigned int*>(u_bf)[row1 * 16 + c1] =
                    (unsigned int)f2bf(pf1.x) | ((unsigned int)f2bf(pf1.z) << 16);
            }
            if (tid >= 192)
                *reinterpret_cast<float2*>(&u_ext[hrow * 40 + (hside ? 38 : 0)]) = pfh;

            if (tile + gs < ntiles) {
                const int r0n = (tile + gs) * 32;
                long g0 = (long)r0n * 9 + tid; if (g0 > fmax4) g0 = fmax4;
                pf0 = ug[g0];
                if (tid < 32) {
                    long g1 = (long)r0n * 9 + 256 + tid; if (g1 > fmax4) g1 = fmax4;
                    pf1 = ug[g1];
                }
                if (tid >= 192) {
                    int rr = r0n + hrow; if (rr > N - 1) rr = N - 1;
                    pfh = *reinterpret_cast<const float2*>(u + (size_t)rr * 36 + (hside ? 0 : 34));
                }
            }
        }
        __syncthreads();  // bar1: u ready

        // ---- GEMM1 swapped: lane -> h[row=ln][4 consecutive hidden]; 1 b64 write each ----
#pragma unroll
        for (int rb = 0; rb < 2; ++rb) {
            const short8 a1 = *reinterpret_cast<const short8*>(
                &u_bf[(rb * 16 + ln) * 32 + lg * 8]);
#pragma unroll
            for (int t = 0; t < 2; ++t) {
                const f32x4 h4 = mfma_bf16(b1f[t], a1, bias1v[t]);   // SWAPPED -> h^T
                const unsigned int p0 =
                    (unsigned int)f2bf(tanh_fast(h4[0])) |
                    ((unsigned int)f2bf(tanh_fast(h4[1])) << 16);
                const unsigned int p1 =
                    (unsigned int)f2bf(tanh_fast(h4[2])) |
                    ((unsigned int)f2bf(tanh_fast(h4[3])) << 16);
                *reinterpret_cast<uint2*>(
                    &h_sh[(rb * 16 + ln) * 136 + nb + t * 16 + lg * 4]) =
                    make_uint2(p0, p1);
            }
        }
        __syncthreads();  // bar2: h ready

        // ---- GEMM2 swapped: same h_sh b128 reads; acc = C2[row=ln][4 consec features] ----
        f32x4 acc2[2][2];
#pragma unroll
        for (int rb = 0; rb < 2; ++rb)
#pragma unroll
            for (int t = 0; t < 2; ++t) acc2[rb][t] = bias2v[t];

#pragma unroll
        for (int rb = 0; rb < 2; ++rb) {
            const int arow = rb * 16 + ln;
#pragma unroll
            for (int kk = 0; kk < 4; ++kk) {
                const short8 a2 = *reinterpret_cast<const short8*>(
                    &h_sh[arow * 136 + kk * 32 + lg * 8]);
#pragma unroll
                for (int t = 0; t < 2; ++t)
                    acc2[rb][t] = mfma_bf16(b2f[t][kk], a2, acc2[rb][t]);  // SWAPPED
            }
        }

        // ---- C2 -> LDS: b128 for odd-section quads, scalar for even-section ----
#pragma unroll
        for (int rb = 0; rb < 2; ++rb) {
            const int rbase = (rb * 16 + ln) * 144;
#pragma unroll
            for (int t = 0; t < 2; ++t) {
                if (c2vec[t]) {
                    *reinterpret_cast<f32x4*>(&c2s[rbase + c2slot[t][0]]) = acc2[rb][t];
                } else {
#pragma unroll
                    for (int r = 0; r < 4; ++r)
                        if (c2slot[t][r] >= 0)
                            c2s[rbase + c2slot[t][r]] = acc2[rb][t][r];
                }
            }
        }
        __syncthreads();  // bar3: c2 ready

        // ---- epilogue (byte-identical to R8) ----
        const int r0 = tile * 32;
#pragma unroll
        for (int s = 0; s < 3; ++s) {
            const int w = s * 256 + tid;
            if (w < 576) {
                const int row = w / 18;
                const int i   = w - row * 18;
                const int rg  = r0 + row;

                const float2 v0 = *reinterpret_cast<const float2*>(&u_ext[row * 40 + 2 * i]);
                const float2 v1 = *reinterpret_cast<const float2*>(&u_ext[row * 40 + 2 * i + 2]);
                const float2 v2 = *reinterpret_cast<const float2*>(&u_ext[row * 40 + 2 * i + 4]);
                const f32x4  q0 = *reinterpret_cast<const f32x4*>(&c2s[row * 144 + 8 * i]);
                const f32x4  q1 = *reinterpret_cast<const f32x4*>(&c2s[row * 144 + 8 * i + 4]);

                const float um2 = v0.x, uA = v0.y;
                const float ue  = v1.x, uo = v1.y;
                const float up2 = v2.x, uC = v2.y;

                const float oe = q0[0] + q0[1] * uA + q0[2] * uo;
                const float oo = q1[0] + q1[1] * uA + q1[2] * uo + q1[3] * uC;

                float re = r10;
                re = fmaf(r11, ue,       re);
                re = fmaf(r12, uo,       re);
                re = fmaf(r13, um2 * uA, re);
                re = fmaf(r14, uA * up2, re);
                re = fmaf(r15, ue * uo,  re);

                float ro = r20;
                ro = fmaf(r21, uo,       ro);
                ro = fmaf(r22, uA * ue,  ro);
                ro = fmaf(r23, ue * up2, ro);

                if (rg < N)
                    *reinterpret_cast<float2*>(out + (size_t)rg * 36 + 2 * i) =
                        make_float2(oe + re, oo + ro);
            }
        }
        __syncthreads();  // bar4: buffers free for next staging
    }
}

extern "C" void kernel_launch(void* const* d_in, const int* in_sizes, int n_in,
                              void* d_out, int out_size, void* d_ws, size_t ws_size,
                              hipStream_t stream) {
    // d_in order: t, u, reg1, reg2, W1, b1, W2a, b2a, W2b, b2b
    const float* u    = (const float*)d_in[1];
    const float* reg1 = (const float*)d_in[2];
    const float* reg2 = (const float*)d_in[3];
    const float* W1   = (const float*)d_in[4];
    const float* b1   = (const float*)d_in[5];
    const float* W2a  = (const float*)d_in[6];
    const float* b2a  = (const float*)d_in[7];
    const float* W2b  = (const float*)d_in[8];
    const float* b2b  = (const float*)d_in[9];
    float* out = (float*)d_out;

    const int N = in_sizes[1] / 36;
    const int ntiles = (N + 31) / 32;
    int grid = ntiles < 1024 ? ntiles : 1024;
    if (grid < 1) grid = 1;
    mixmodel_mfma9<<<grid, 256, 0, stream>>>(u, reg1, reg2, W1, b1,
                                             W2a, b2a, W2b, b2b, out, N, ntiles);
}

// Round 10
// 77.508 us; speedup vs baseline: 1.2234x; 1.2234x over previous
//
#include <hip/hip_runtime.h>
#include <cstddef>

// Block-cooperative MFMA MixModel, 32 rows/tile (R10 = conflict-audited merge):
//   GEMM1 SWAPPED (R9-verified): D = mfma(W1frag, u_frag) -> lane holds
//     h[row=ln][4 consecutive k] -> tanh+pack -> 1 ds_write_b64.
//     Write banks (4ln+2lg)%32: 4 accesses/bank = b64 minimum, conflict-free.
//   GEMM2 UNSWAPPED (R8-verified): h_sh [row][k] b128 reads; scalar c2 writes.
//   c2s stride 144 -> 148 dwords (148%32=20): write banks (16lg+20r+slot)%32 ~2-way;
//     epilogue b128 read start-banks = all multiples of 4 -> balanced (was 2x at 144).
// u staging, h_sh reads, epilogue logic: byte-identical to R8.

typedef __attribute__((ext_vector_type(8))) __bf16 bf16x8;
typedef __attribute__((ext_vector_type(8))) short short8;
typedef __attribute__((ext_vector_type(4))) float f32x4;

__device__ __forceinline__ unsigned short f2bf(float f) {
    // manual RNE float->bf16 (R4/R6/R8/R9-verified)
    unsigned int u = __float_as_uint(f);
    unsigned int r = (u + 0x7FFFu + ((u >> 16) & 1u)) >> 16;
    return (unsigned short)r;
}

// --- mfma wrapper: tolerate either V8bf16 or V8i16 builtin signature ---
template <typename A>
__device__ __forceinline__ auto mfma_try(A a, A b, f32x4 c, int)
    -> decltype(__builtin_amdgcn_mfma_f32_16x16x32_bf16(a, b, c, 0, 0, 0)) {
    return __builtin_amdgcn_mfma_f32_16x16x32_bf16(a, b, c, 0, 0, 0);
}
template <typename A>
__device__ __forceinline__ f32x4 mfma_try(A a, A b, f32x4 c, long) {
    return __builtin_amdgcn_mfma_f32_16x16x32_bf16(
        __builtin_bit_cast(short8, a), __builtin_bit_cast(short8, b), c, 0, 0, 0);
}
__device__ __forceinline__ f32x4 mfma_bf16(short8 a, short8 b, f32x4 c) {
    return mfma_try(__builtin_bit_cast(bf16x8, a), __builtin_bit_cast(bf16x8, b), c, 0);
}

__device__ __forceinline__ float tanh_fast(float x) {
    const float e2 = __expf(2.0f * x);
    return 1.0f - __fdividef(2.0f, e2 + 1.0f);
}

__global__ __launch_bounds__(256, 4) void mixmodel_mfma10(
    const float* __restrict__ u,      // N*36
    const float* __restrict__ reg1,   // 6
    const float* __restrict__ reg2,   // 4
    const float* __restrict__ W1,     // 18*128
    const float* __restrict__ b1,     // 128
    const float* __restrict__ W2a,    // 128*54
    const float* __restrict__ b2a,    // 54
    const float* __restrict__ W2b,    // 128*72
    const float* __restrict__ b2b,    // 72
    float* __restrict__ out,          // N*36
    int N, int ntiles)
{
    __shared__ __align__(16) float          u_ext[32 * 40];   // 5120 B
    __shared__ __align__(16) unsigned short h_sh[32 * 136];   // 8704 B (verified layout)
    __shared__ __align__(16) unsigned short u_bf[32 * 32];    // 2048 B
    __shared__ __align__(16) float          c2s[32 * 148];    // 18944 B, [row][8i+slot], stride 148
    // total = 34816 B -> 4 blocks/CU

    const int tid = threadIdx.x;
    const int wid = tid >> 6;
    const int l   = tid & 63;
    const int ln  = l & 15;
    const int lg  = l >> 4;
    const int nb  = wid * 32;

    reinterpret_cast<unsigned int*>(u_bf)[tid]       = 0u;
    reinterpret_cast<unsigned int*>(u_bf)[tid + 256] = 0u;
    __syncthreads();

    // ---- resident weight fragments (R8 data, R8 54-offset map): 40 VGPRs ----
    short8 b1f[2];
    short8 b2f[2][4];
    f32x4 bias1v[2];            // per-reg bias for swapped GEMM1 (R9-verified)
    float bias2[2];             // per-lane bias for unswapped GEMM2 (R8-verified)
    int c2idx[2];               // quad-interleaved in-row index (max 143)
#pragma unroll
    for (int t = 0; t < 2; ++t) {
        const int n = nb + t * 16 + ln;
        short8 v;
#pragma unroll
        for (int j = 0; j < 8; ++j) {
            const int k = lg * 8 + j;
            const float w = (k < 18) ? W1[k * 128 + n] : 0.0f;
            v[j] = (short)f2bf(w);
        }
        b1f[t] = v;
        bias1v[t] = *reinterpret_cast<const f32x4*>(&b1[nb + t * 16 + lg * 4]);
        bias2[t] = (n < 54) ? b2a[n] : (n < 126 ? b2b[n - 54] : 0.0f);
        if (n < 54)       c2idx[t] = (n / 3) * 8 + (n % 3);
        else if (n < 126) { const int m = n - 54; c2idx[t] = (m >> 2) * 8 + 4 + (m & 3); }
        else              c2idx[t] = 3;  // dump slot, never read
#pragma unroll
        for (int kk = 0; kk < 4; ++kk) {
            short8 w2;
#pragma unroll
            for (int j = 0; j < 8; ++j) {
                const int k = kk * 32 + lg * 8 + j;
                float w;
                if (n < 54)       w = W2a[k * 54 + n];
                else if (n < 126) w = W2b[k * 72 + (n - 54)];
                else              w = 0.0f;
                w2[j] = (short)f2bf(w);
            }
            b2f[t][kk] = w2;
        }
    }

    // ---- regression coefficients (wave-uniform -> SGPR) ----
    const float r10 = reg1[0], r11 = reg1[1], r12 = reg1[2];
    const float r13 = reg1[3], r14 = reg1[4], r15 = reg1[5];
    const float r20 = reg2[0], r21 = reg2[1], r22 = reg2[2], r23 = reg2[3];

    const float4* ug = reinterpret_cast<const float4*>(u);
    const long fmax4 = (long)N * 9 - 1;
    const int gs = gridDim.x;

    // ---- staging maps (R8-verified) ----
    const int row0 = tid / 9,          c0 = tid - row0 * 9;
    const int row1 = (256 + tid) / 9,  c1 = (256 + tid) - row1 * 9;
    const int hrow = (tid - 192) >> 1, hside = tid & 1;

    float4 pf0, pf1; float2 pfh;
    {
        const int r0 = blockIdx.x * 32;
        long g0 = (long)r0 * 9 + tid; if (g0 > fmax4) g0 = fmax4;
        pf0 = ug[g0];
        if (tid < 32) {
            long g1 = (long)r0 * 9 + 256 + tid; if (g1 > fmax4) g1 = fmax4;
            pf1 = ug[g1];
        }
        if (tid >= 192) {
            int rr = r0 + hrow; if (rr > N - 1) rr = N - 1;
            pfh = *reinterpret_cast<const float2*>(u + (size_t)rr * 36 + (hside ? 0 : 34));
        }
    }

    for (int tile = blockIdx.x; tile < ntiles; tile += gs) {
        // ---- stage u_ext / u_bf; prefetch next (R8-verified) ----
        {
            float* dst = &u_ext[row0 * 40 + 2 + c0 * 4];
            reinterpret_cast<float2*>(dst)[0] = make_float2(pf0.x, pf0.y);
            reinterpret_cast<float2*>(dst)[1] = make_float2(pf0.z, pf0.w);
            reinterpret_cast<unsigned int*>(u_bf)[row0 * 16 + c0] =
                (unsigned int)f2bf(pf0.x) | ((unsigned int)f2bf(pf0.z) << 16);
            if (tid < 32) {
                float* dst1 = &u_ext[row1 * 40 + 2 + c1 * 4];
                reinterpret_cast<float2*>(dst1)[0] = make_float2(pf1.x, pf1.y);
                reinterpret_cast<float2*>(dst1)[1] = make_float2(pf1.z, pf1.w);
                reinterpret_cast<unsigned int*>(u_bf)[row1 * 16 + c1] =
                    (unsigned int)f2bf(pf1.x) | ((unsigned int)f2bf(pf1.z) << 16);
            }
            if (tid >= 192)
                *reinterpret_cast<float2*>(&u_ext[hrow * 40 + (hside ? 38 : 0)]) = pfh;

            if (tile + gs < ntiles) {
                const int r0n = (tile + gs) * 32;
                long g0 = (long)r0n * 9 + tid; if (g0 > fmax4) g0 = fmax4;
                pf0 = ug[g0];
                if (tid < 32) {
                    long g1 = (long)r0n * 9 + 256 + tid; if (g1 > fmax4) g1 = fmax4;
                    pf1 = ug[g1];
                }
                if (tid >= 192) {
                    int rr = r0n + hrow; if (rr > N - 1) rr = N - 1;
                    pfh = *reinterpret_cast<const float2*>(u + (size_t)rr * 36 + (hside ? 0 : 34));
                }
            }
        }
        __syncthreads();  // bar1: u ready

        // ---- GEMM1 SWAPPED (R9-verified): 1 ds_write_b64 per (rb,t) ----
#pragma unroll
        for (int rb = 0; rb < 2; ++rb) {
            const short8 a1 = *reinterpret_cast<const short8*>(
                &u_bf[(rb * 16 + ln) * 32 + lg * 8]);
#pragma unroll
            for (int t = 0; t < 2; ++t) {
                const f32x4 h4 = mfma_bf16(b1f[t], a1, bias1v[t]);   // SWAPPED -> h^T
                const unsigned int p0 =
                    (unsigned int)f2bf(tanh_fast(h4[0])) |
                    ((unsigned int)f2bf(tanh_fast(h4[1])) << 16);
                const unsigned int p1 =
                    (unsigned int)f2bf(tanh_fast(h4[2])) |
                    ((unsigned int)f2bf(tanh_fast(h4[3])) << 16);
                *reinterpret_cast<uint2*>(
                    &h_sh[(rb * 16 + ln) * 136 + nb + t * 16 + lg * 4]) =
                    make_uint2(p0, p1);
            }
        }
        __syncthreads();  // bar2: h ready

        // ---- GEMM2 UNSWAPPED (R8-verified): b128 reads, 16 MFMA ----
        f32x4 acc2[2][2];
#pragma unroll
        for (int rb = 0; rb < 2; ++rb)
#pragma unroll
            for (int t = 0; t < 2; ++t) acc2[rb][t] = (f32x4)bias2[t];

#pragma unroll
        for (int rb = 0; rb < 2; ++rb) {
            const int arow = rb * 16 + ln;
#pragma unroll
            for (int kk = 0; kk < 4; ++kk) {
                const short8 a2 = *reinterpret_cast<const short8*>(
                    &h_sh[arow * 136 + kk * 32 + lg * 8]);
#pragma unroll
                for (int t = 0; t < 2; ++t)
                    acc2[rb][t] = mfma_bf16(a2, b2f[t][kk], acc2[rb][t]);
            }
        }

        // ---- C2 -> LDS (R8 pattern, stride 148) ----
#pragma unroll
        for (int rb = 0; rb < 2; ++rb)
#pragma unroll
            for (int t = 0; t < 2; ++t)
#pragma unroll
                for (int r = 0; r < 4; ++r)
                    c2s[(rb * 16 + lg * 4 + r) * 148 + c2idx[t]] = acc2[rb][t][r];
        __syncthreads();  // bar3: c2 ready

        // ---- epilogue (R8-verified, stride 148) ----
        const int r0 = tile * 32;
#pragma unroll
        for (int s = 0; s < 3; ++s) {
            const int w = s * 256 + tid;
            if (w < 576) {
                const int row = w / 18;
                const int i   = w - row * 18;
                const int rg  = r0 + row;

                const float2 v0 = *reinterpret_cast<const float2*>(&u_ext[row * 40 + 2 * i]);
                const float2 v1 = *reinterpret_cast<const float2*>(&u_ext[row * 40 + 2 * i + 2]);
                const float2 v2 = *reinterpret_cast<const float2*>(&u_ext[row * 40 + 2 * i + 4]);
                const f32x4  q0 = *reinterpret_cast<const f32x4*>(&c2s[row * 148 + 8 * i]);
                const f32x4  q1 = *reinterpret_cast<const f32x4*>(&c2s[row * 148 + 8 * i + 4]);

                const float um2 = v0.x, uA = v0.y;
                const float ue  = v1.x, uo = v1.y;
                const float up2 = v2.x, uC = v2.y;

                const float oe = q0[0] + q0[1] * uA + q0[2] * uo;
                const float oo = q1[0] + q1[1] * uA + q1[2] * uo + q1[3] * uC;

                float re = r10;
                re = fmaf(r11, ue,       re);
                re = fmaf(r12, uo,       re);
                re = fmaf(r13, um2 * uA, re);
                re = fmaf(r14, uA * up2, re);
                re = fmaf(r15, ue * uo,  re);

                float ro = r20;
                ro = fmaf(r21, uo,       ro);
                ro = fmaf(r22, uA * ue,  ro);
                ro = fmaf(r23, ue * up2, ro);

                if (rg < N)
                    *reinterpret_cast<float2*>(out + (size_t)rg * 36 + 2 * i) =
                        make_float2(oe + re, oo + ro);
            }
        }
        __syncthreads();  // bar4: buffers free for next staging
    }
}

extern "C" void kernel_launch(void* const* d_in, const int* in_sizes, int n_in,
                              void* d_out, int out_size, void* d_ws, size_t ws_size,
                              hipStream_t stream) {
    // d_in order: t, u, reg1, reg2, W1, b1, W2a, b2a, W2b, b2b
    const float* u    = (const float*)d_in[1];
    const float* reg1 = (const float*)d_in[2];
    const float* reg2 = (const float*)d_in[3];
    const float* W1   = (const float*)d_in[4];
    const float* b1   = (const float*)d_in[5];
    const float* W2a  = (const float*)d_in[6];
    const float* b2a  = (const float*)d_in[7];
    const float* W2b  = (const float*)d_in[8];
    const float* b2b  = (const float*)d_in[9];
    float* out = (float*)d_out;

    const int N = in_sizes[1] / 36;
    const int ntiles = (N + 31) / 32;
    int grid = ntiles < 1024 ? ntiles : 1024;
    if (grid < 1) grid = 1;
    mixmodel_mfma10<<<grid, 256, 0, stream>>>(u, reg1, reg2, W1, b1,
                                              W2a, b2a, W2b, b2b, out, N, ntiles);
}